// Round 3
// baseline (40.859 us; speedup 1.0000x reference)
//
#include <hip/hip_runtime.h>

// LengthRegulator: x[B,T,D] f32, duration[B,T] i32 -> out[B,M,D] f32 (+ mel_len[B] as f32 tail)
// B=32, T=512, D=384, M=4096.
#define B_SZ 32
#define T_PH 512
#define D_MOD 384
#define D4 (D_MOD / 4)               // 96 float4 per row
#define M_MEL 4096
#define UNITS_PER_BATCH (M_MEL * D4) // 393216 float4 units per batch
#define GRID_X 96
#define BLK 512
#define STRIDE (GRID_X * BLK)        // 49152 = 512*96  -> d4 invariant, t += 512 per iter
#define ITERS (UNITS_PER_BATCH / STRIDE)  // exactly 8

typedef float fx4 __attribute__((ext_vector_type(4)));

__global__ __launch_bounds__(BLK)
void lr_expand_kernel(const fx4* __restrict__ x,
                      const int* __restrict__ duration,
                      fx4* __restrict__ out,
                      float* __restrict__ mel_out) {
    __shared__ int cum[T_PH];
    __shared__ int wsum[8];

    const int b   = blockIdx.y;
    const int tid = threadIdx.x;
    const int lane = tid & 63;
    const int wid  = tid >> 6;

    // ---- inclusive scan of clamped durations for this batch (512 elems, 8 waves) ----
    int v = duration[b * T_PH + tid];
    v = v < 0 ? 0 : v;

    #pragma unroll
    for (int off = 1; off < 64; off <<= 1) {
        int n = __shfl_up(v, off, 64);
        if (lane >= off) v += n;
    }
    if (lane == 63) wsum[wid] = v;
    __syncthreads();
    if (tid == 0) {
        int s = 0;
        #pragma unroll
        for (int i = 0; i < 8; ++i) { s += wsum[i]; wsum[i] = s; }
    }
    __syncthreads();
    const int add = (wid > 0) ? wsum[wid - 1] : 0;
    cum[tid] = v + add;
    __syncthreads();

    const int mel_len = cum[T_PH - 1];
    if (blockIdx.x == 0 && tid == 0) {
        mel_out[b] = (float)mel_len;
    }

    // ---- expand: each thread owns a fixed d4 column slot; t steps by 512 ----
    const fx4* xb = x   + (size_t)b * T_PH * D4;
    fx4*       ob = out + (size_t)b * M_MEL * D4;
    const fx4 zero = (fx4){0.f, 0.f, 0.f, 0.f};

    const int u0 = blockIdx.x * BLK + tid;
    const int t0 = u0 / D4;           // one division per thread
    const int d4 = u0 - t0 * D4;

    #pragma unroll
    for (int k = 0; k < ITERS; ++k) {
        const int t = t0 + k * 512;
        const int u = u0 + k * STRIDE;
        fx4 val = zero;
        if (t < mel_len) {
            // searchsorted(cum, t, side='right'): first i with cum[i] > t
            int lo = 0, hi = T_PH - 1;
            while (lo < hi) {
                const int mid = (lo + hi) >> 1;
                if (cum[mid] <= t) lo = mid + 1; else hi = mid;
            }
            val = xb[lo * D4 + d4];
        }
        __builtin_nontemporal_store(val, &ob[u]);   // stream out past L2
    }
}

extern "C" void kernel_launch(void* const* d_in, const int* in_sizes, int n_in,
                              void* d_out, int out_size, void* d_ws, size_t ws_size,
                              hipStream_t stream) {
    const fx4* x   = (const fx4*)d_in[0];
    const int* dur = (const int*)d_in[1];
    float* out_f = (float*)d_out;
    fx4*   out   = (fx4*)d_out;
    float* mel_out = out_f + (size_t)B_SZ * M_MEL * D_MOD;  // tail: 32 floats

    dim3 grid(GRID_X, B_SZ);
    dim3 block(BLK);
    lr_expand_kernel<<<grid, block, 0, stream>>>(x, dur, out, mel_out);
}

// Round 4
// 37.393 us; speedup vs baseline: 1.0927x; 1.0927x over previous
//
#include <hip/hip_runtime.h>

// LengthRegulator: x[B,T,D] f32, duration[B,T] i32 -> out[B,M,D] f32 (+ mel_len[B] as f32 tail)
// B=32, T=512, D=384, M=4096.
#define B_SZ 32
#define T_PH 512
#define D_MOD 384
#define D4 (D_MOD / 4)               // 96 float4 per row
#define M_MEL 4096
#define UNITS_PER_BATCH (M_MEL * D4) // 393216 float4 units per batch
#define GRID_X 96
#define BLK 512
#define STRIDE (GRID_X * BLK)        // 49152 = 512*96  -> d4 invariant, t += 512 per iter
#define ITERS (UNITS_PER_BATCH / STRIDE)  // exactly 8

typedef float fx4 __attribute__((ext_vector_type(4)));

__global__ __launch_bounds__(BLK)
void lr_expand_kernel(const fx4* __restrict__ x,
                      const int* __restrict__ duration,
                      fx4* __restrict__ out,
                      float* __restrict__ mel_out) {
    __shared__ int cum[T_PH];
    __shared__ int wsum[8];

    const int b   = blockIdx.y;
    const int tid = threadIdx.x;
    const int lane = tid & 63;
    const int wid  = tid >> 6;

    // ---- inclusive scan of clamped durations for this batch (512 elems, 8 waves) ----
    int v = duration[b * T_PH + tid];
    v = v < 0 ? 0 : v;

    #pragma unroll
    for (int off = 1; off < 64; off <<= 1) {
        int n = __shfl_up(v, off, 64);
        if (lane >= off) v += n;
    }
    if (lane == 63) wsum[wid] = v;
    __syncthreads();
    if (tid == 0) {
        int s = 0;
        #pragma unroll
        for (int i = 0; i < 8; ++i) { s += wsum[i]; wsum[i] = s; }
    }
    __syncthreads();
    const int add = (wid > 0) ? wsum[wid - 1] : 0;
    cum[tid] = v + add;
    __syncthreads();

    const int mel_len = cum[T_PH - 1];
    if (blockIdx.x == 0 && tid == 0) {
        mel_out[b] = (float)mel_len;
    }

    // ---- expand: each thread owns a fixed d4 column slot; t steps by 512 ----
    const fx4* xb = x   + (size_t)b * T_PH * D4;
    fx4*       ob = out + (size_t)b * M_MEL * D4;
    const fx4 zero = (fx4){0.f, 0.f, 0.f, 0.f};

    const int u0 = blockIdx.x * BLK + tid;
    const int t0 = u0 / D4;           // one division per thread
    const int d4 = u0 - t0 * D4;

    #pragma unroll
    for (int k = 0; k < ITERS; ++k) {
        const int t = t0 + k * 512;
        const int u = u0 + k * STRIDE;
        fx4 val = zero;
        if (t < mel_len) {
            // searchsorted(cum, t, side='right'): first i with cum[i] > t
            int lo = 0, hi = T_PH - 1;
            while (lo < hi) {
                const int mid = (lo + hi) >> 1;
                if (cum[mid] <= t) lo = mid + 1; else hi = mid;
            }
            val = xb[lo * D4 + d4];
        }
        ob[u] = val;   // plain cached store — L2 write-combining is a win here
    }
}

extern "C" void kernel_launch(void* const* d_in, const int* in_sizes, int n_in,
                              void* d_out, int out_size, void* d_ws, size_t ws_size,
                              hipStream_t stream) {
    const fx4* x   = (const fx4*)d_in[0];
    const int* dur = (const int*)d_in[1];
    float* out_f = (float*)d_out;
    fx4*   out   = (fx4*)d_out;
    float* mel_out = out_f + (size_t)B_SZ * M_MEL * D_MOD;  // tail: 32 floats

    dim3 grid(GRID_X, B_SZ);
    dim3 block(BLK);
    lr_expand_kernel<<<grid, block, 0, stream>>>(x, dur, out, mel_out);
}